// Round 1
// baseline (510.802 us; speedup 1.0000x reference)
//
#include <hip/hip_runtime.h>
#include <hip/hip_bf16.h>

// Problem constants (match reference setup_inputs)
#define BB 8
#define HH 1024
#define EE 512
#define VV 32000
#define TT 100
#define KV 1536   // H+E
#define KK 2560   // 2H+E

// ---------------------------------------------------------------------------
// Kernel 1: e_v for all (b,w); writes p = exp(tanh(e_v)) to d_out for every
// element, plus per-block per-b partial sums (deterministic, no atomics).
// Each wave handles 4 consecutive W_V rows; lane owns a fixed j-slice so x_v
// LDS reads are amortized across the 4 rows (LDS traffic = 2x HBM traffic).
// ---------------------------------------------------------------------------
__global__ __launch_bounds__(256) void ev_kernel(
    const float* __restrict__ output, const float* __restrict__ input_step,
    const float* __restrict__ W_V, const float* __restrict__ b_V,
    float* __restrict__ d_out, float* __restrict__ blocksums) {
  __shared__ float xv[BB * KV];          // 49152 B
  __shared__ float wavesums[4][8];

  const int tid = threadIdx.x;

  // Stage x_v = concat(output, input_step) per batch into LDS (coalesced f4)
  for (int i = tid; i < BB * KV / 4; i += 256) {   // 3072 float4s
    int b = i / (KV / 4);                          // /384
    int pos = (i - b * (KV / 4)) * 4;
    float4 v;
    if (pos < HH) v = *(const float4*)(output + b * HH + pos);
    else          v = *(const float4*)(input_step + b * EE + (pos - HH));
    *(float4*)(xv + b * KV + pos) = v;
  }
  __syncthreads();

  const int wave = tid >> 6;
  const int lane = tid & 63;
  const int w0 = blockIdx.x * 16 + wave * 4;       // 4 rows per wave

  float acc[4][8];
#pragma unroll
  for (int r = 0; r < 4; ++r)
#pragma unroll
    for (int b = 0; b < 8; ++b) acc[r][b] = 0.f;

#pragma unroll 2
  for (int jg = 0; jg < 6; ++jg) {
    const int jb = jg * 256 + lane * 4;
    float4 wv0 = *(const float4*)(W_V + (size_t)(w0 + 0) * KV + jb);
    float4 wv1 = *(const float4*)(W_V + (size_t)(w0 + 1) * KV + jb);
    float4 wv2 = *(const float4*)(W_V + (size_t)(w0 + 2) * KV + jb);
    float4 wv3 = *(const float4*)(W_V + (size_t)(w0 + 3) * KV + jb);
#pragma unroll
    for (int b = 0; b < 8; ++b) {
      float4 x = *(const float4*)(xv + b * KV + jb);
      acc[0][b] += wv0.x * x.x + wv0.y * x.y + wv0.z * x.z + wv0.w * x.w;
      acc[1][b] += wv1.x * x.x + wv1.y * x.y + wv1.z * x.z + wv1.w * x.w;
      acc[2][b] += wv2.x * x.x + wv2.y * x.y + wv2.z * x.z + wv2.w * x.w;
      acc[3][b] += wv3.x * x.x + wv3.y * x.y + wv3.z * x.z + wv3.w * x.w;
    }
  }

  // Butterfly-reduce each of the 32 accumulators over 64 lanes; deposit the
  // (r,b) result into lane r*8+b (compile-time indices only -> stays in regs)
  float myval = 0.f;
#pragma unroll
  for (int r = 0; r < 4; ++r) {
#pragma unroll
    for (int b = 0; b < 8; ++b) {
      float v = acc[r][b];
#pragma unroll
      for (int off = 32; off; off >>= 1) v += __shfl_xor(v, off, 64);
      if (lane == r * 8 + b) myval = v;
    }
  }

  float p = 0.f;
  if (lane < 32) {
    const int r = lane >> 3;
    const int b = lane & 7;
    const int w = w0 + r;
    float ev = myval + b_V[w];
    p = expf(tanhf(ev));                       // |ev_tanh| <= 1: no max needed
    d_out[(size_t)b * VV + w] = p;
  }
  // per-b partial sums: fold r (xor 8,16) and the idle upper half (xor 32)
  p += __shfl_xor(p, 8, 64);
  p += __shfl_xor(p, 16, 64);
  p += __shfl_xor(p, 32, 64);
  if (lane < 8) wavesums[wave][lane] = p;
  __syncthreads();
  if (tid < 8) {
    float s = wavesums[0][tid] + wavesums[1][tid] + wavesums[2][tid] + wavesums[3][tid];
    blocksums[(size_t)blockIdx.x * 8 + tid] = s;
  }
}

// ---------------------------------------------------------------------------
// Kernel 2: topic corrections. One wave per (b,t). First-occurrence waves
// compute e_k = x_k . W_K[w] + b_K[w], p = exp(tanh(k*e_k)), overwrite
// d_out[b,w] and record delta = p_new - p_old for the softmax sum.
// ---------------------------------------------------------------------------
__global__ __launch_bounds__(256) void topic_kernel(
    const float* __restrict__ output, const float* __restrict__ input_step,
    const float* __restrict__ context, const int* __restrict__ topic_idx,
    const float* __restrict__ W_K, const float* __restrict__ b_K,
    float* __restrict__ d_out, float* __restrict__ topic_delta) {
  const int wave = threadIdx.x >> 6;
  const int lane = threadIdx.x & 63;
  const int task = blockIdx.x * 4 + wave;          // < 800
  const int b = task / TT;
  const int t = task - b * TT;
  const int w = topic_idx[b * TT + t];

  bool valid = (w != 0);
  int k = 0, first = TT;
  if (valid) {
    for (int t2 = 0; t2 < TT; ++t2) {
      int w2 = topic_idx[b * TT + t2];
      if (w2 == w) { ++k; if (t2 < first) first = t2; }
    }
    valid = (first == t);                          // dedup: first occurrence
  }
  if (!valid) {
    if (lane == 0) topic_delta[task] = 0.f;
    return;
  }

  float s = 0.f;
#pragma unroll
  for (int i = 0; i < 10; ++i) {
    const int j = i * 256 + lane * 4;
    float4 wk = *(const float4*)(W_K + (size_t)w * KK + j);
    const float* xs;
    if (j < HH)            xs = output + b * HH + j;
    else if (j < HH + EE)  xs = input_step + b * EE + (j - HH);
    else                   xs = context + b * HH + (j - HH - EE);
    float4 x = *(const float4*)xs;
    s += wk.x * x.x + wk.y * x.y + wk.z * x.z + wk.w * x.w;
  }
#pragma unroll
  for (int off = 32; off; off >>= 1) s += __shfl_xor(s, off, 64);

  float ek = s + b_K[w];
  float p = expf(tanhf((float)k * ek));
  if (lane == 0) {
    float pold = d_out[(size_t)b * VV + w];
    d_out[(size_t)b * VV + w] = p;
    topic_delta[task] = p - pold;
  }
}

// ---------------------------------------------------------------------------
// Kernel 3: sums[b] = sum(blocksums[:,b]) + sum(topic_delta[b,:])
// ---------------------------------------------------------------------------
__global__ __launch_bounds__(256) void reduce_kernel(
    const float* __restrict__ blocksums, const float* __restrict__ topic_delta,
    float* __restrict__ sums, int nblocks) {
  const int b = blockIdx.x;
  const int tid = threadIdx.x;
  float s = 0.f;
  for (int i = tid; i < nblocks; i += 256) s += blocksums[(size_t)i * 8 + b];
  if (tid < TT) s += topic_delta[b * TT + tid];
  __shared__ float red[4];
#pragma unroll
  for (int off = 32; off; off >>= 1) s += __shfl_xor(s, off, 64);
  if ((tid & 63) == 0) red[tid >> 6] = s;
  __syncthreads();
  if (tid == 0) sums[b] = red[0] + red[1] + red[2] + red[3];
}

// ---------------------------------------------------------------------------
// Kernel 4: normalize in place (float4)
// ---------------------------------------------------------------------------
__global__ __launch_bounds__(256) void norm_kernel(
    float* __restrict__ d_out, const float* __restrict__ sums) {
  const int i = blockIdx.x * 256 + threadIdx.x;    // float4 index, 64000 total
  const int b = i / (VV / 4);                      // /8000
  float4 v = *((const float4*)d_out + i);
  const float s = sums[b];
  v.x /= s; v.y /= s; v.z /= s; v.w /= s;
  *((float4*)d_out + i) = v;
}

extern "C" void kernel_launch(void* const* d_in, const int* in_sizes, int n_in,
                              void* d_out, int out_size, void* d_ws, size_t ws_size,
                              hipStream_t stream) {
  const float* output     = (const float*)d_in[0];
  const float* input_step = (const float*)d_in[1];
  const float* context    = (const float*)d_in[2];
  const int*   topic_idx  = (const int*)d_in[3];
  // d_in[4] = topic_length scalar (100), unused: hardcoded
  const float* W_V = (const float*)d_in[5];
  const float* b_V = (const float*)d_in[6];
  const float* W_K = (const float*)d_in[7];
  const float* b_K = (const float*)d_in[8];
  float* out = (float*)d_out;

  float* ws_f        = (float*)d_ws;
  float* topic_delta = ws_f;                 // 800 floats
  float* blocksums   = ws_f + 800;           // 2000*8 floats
  float* sums        = ws_f + 800 + 16000;   // 8 floats

  const int nblocks = VV / 16;               // 2000: 16 rows per block

  ev_kernel<<<nblocks, 256, 0, stream>>>(output, input_step, W_V, b_V, out, blocksums);
  topic_kernel<<<(BB * TT) / 4, 256, 0, stream>>>(output, input_step, context,
                                                  topic_idx, W_K, b_K, out, topic_delta);
  reduce_kernel<<<BB, 256, 0, stream>>>(blocksums, topic_delta, sums, nblocks);
  norm_kernel<<<(VV / 4) * BB / 256, 256, 0, stream>>>(out, sums);
}